// Round 19
// baseline (303.740 us; speedup 1.0000x reference)
//
#include <hip/hip_runtime.h>
#include <math.h>

#define B_ 32
#define N_ 512
#define F_ 101
#define E_ 128
#define H_ 4
#define EH_ 512
#define L_ 3
#define M_ (B_*N_)   // 16384

typedef __attribute__((ext_vector_type(8))) short s8v;
typedef __attribute__((ext_vector_type(8))) unsigned short us8v;
typedef __attribute__((ext_vector_type(4))) float f4v;
typedef __attribute__((ext_vector_type(4))) unsigned int u4v;

__device__ __forceinline__ unsigned short f2bf(float f){
  unsigned int u = __builtin_bit_cast(unsigned int, f);
  u += 0x7fffu + ((u>>16)&1u);
  return (unsigned short)(u>>16);
}
__device__ __forceinline__ float bf2f(unsigned int h){
  unsigned int u = h<<16; return __builtin_bit_cast(float, u);
}
__device__ __forceinline__ float softplus_f(float v) {
  return fmaxf(v, 0.f) + log1pf(__expf(-fabsf(v)));
}

#define GLOAD16(gp, lp) __builtin_amdgcn_global_load_lds( \
    (__attribute__((address_space(1))) unsigned int*)(gp), \
    (__attribute__((address_space(3))) unsigned int*)(lp), 16, 0, 0)

#define MFMA16(a,b,c) __builtin_amdgcn_mfma_f32_16x16x32_bf16(a,b,c,0,0,0)

// ---------- prepA: effp (blk<384) + effb_part (blk>=384) ----------
__global__ __launch_bounds__(256) void prepA_kernel(
    const float* __restrict__ wq, const float* __restrict__ wk,
    const float* __restrict__ bq, const float* __restrict__ bk,
    const float* __restrict__ inproj_w,
    float* __restrict__ effpart, float* __restrict__ bpart) {
  __shared__ float As[64][132];   // [kk][r]
  __shared__ float Bs[64][68];    // [kk][c]
  const int blk = blockIdx.x;
  const int t = threadIdx.x;
  if (blk < 384) {
    const int bx = blk % 48, ks = blk / 48;
    const int lq = bx>>3, nt = bx&7;
    const int l = lq>>1, qk = lq&1;
    const int bn = nt*64;
    const int k0 = ks*64;
    const float* A = (qk ? wk : wq) + (size_t)l*128*512;
    const float* IP = inproj_w + (size_t)l*512*1536 + qk*512 + bn;
    float acc[8][4];
    #pragma unroll
    for (int i=0;i<8;++i)
      #pragma unroll
      for (int j=0;j<4;++j) acc[i][j]=0.f;
    const int r0 = (t&15)*8, c0 = (t>>4)*4;
    {
      int r = t & 127, half = t>>7;
      #pragma unroll
      for (int u=0;u<8;++u){
        float4 a = *(const float4*)(A + (size_t)r*512 + k0 + half*32 + u*4);
        int kk = half*32 + u*4;
        As[kk+0][r]=a.x; As[kk+1][r]=a.y; As[kk+2][r]=a.z; As[kk+3][r]=a.w;
      }
      int kk = t>>2, cb = (t&3)*16;
      #pragma unroll
      for (int u=0;u<4;++u)
        *(float4*)&Bs[kk][cb+u*4] = *(const float4*)(IP + (size_t)(k0+kk)*1536 + cb + u*4);
    }
    __syncthreads();
    for (int k2=0;k2<64;++k2){
      float4 b = *(const float4*)&Bs[k2][c0];
      float4 a0 = *(const float4*)&As[k2][r0];
      float4 a1 = *(const float4*)&As[k2][r0+4];
      float av[8] = {a0.x,a0.y,a0.z,a0.w,a1.x,a1.y,a1.z,a1.w};
      #pragma unroll
      for (int i=0;i<8;++i){
        acc[i][0] += av[i]*b.x; acc[i][1] += av[i]*b.y;
        acc[i][2] += av[i]*b.z; acc[i][3] += av[i]*b.w;
      }
    }
    #pragma unroll
    for (int j=0;j<4;++j){
      float* dst = effpart + (((size_t)ks*48 + bx)*64 + c0 + j)*128 + r0;
      float4 v0 = {acc[0][j], acc[1][j], acc[2][j], acc[3][j]};
      float4 v1 = {acc[4][j], acc[5][j], acc[6][j], acc[7][j]};
      *(float4*)dst = v0;
      *(float4*)(dst+4) = v1;
    }
  } else {
    const int idxb = blk - 384;           // 0..47
    const int lq = idxb>>3, kt = idxb&7;
    const int l = lq>>1, qk = lq&1;
    const float* bv = (qk?bk:bq) + l*512 + kt*64;
    const float* IP = inproj_w + ((size_t)l*512 + kt*64)*1536 + qk*512;
    float a0=0.f, a1=0.f;
    for (int kk=0; kk<64; ++kk){
      float b = bv[kk];
      const float* row = IP + (size_t)kk*1536;
      a0 += b*row[t];
      a1 += b*row[t+256];
    }
    bpart[(lq*8+kt)*512 + t]       = a0;
    bpart[(lq*8+kt)*512 + t + 256] = a1;
  }
}

// ---------- prepB: effred | wtrans+bqkv | embW1 | feat ----------
__global__ __launch_bounds__(256) void prepB_kernel(
    const float* __restrict__ effpart, const float* __restrict__ bpart,
    const float* __restrict__ wv, const float* __restrict__ out_w,
    const float* __restrict__ ffn_w,
    const float* __restrict__ inproj_b, const float* __restrict__ bvv,
    const float* __restrict__ emb_w, const float* __restrict__ comp_w,
    const float* __restrict__ str_fea, const int* __restrict__ comp_fea,
    const float* __restrict__ af_table,
    unsigned short* __restrict__ wqkvT, unsigned short* __restrict__ outT,
    unsigned short* __restrict__ ffnT, float* __restrict__ bqkv,
    unsigned short* __restrict__ WHi, unsigned short* __restrict__ WLo,
    float* __restrict__ Cpart,
    unsigned short* __restrict__ FHi, unsigned short* __restrict__ FLo,
    float* __restrict__ w_row) {
  const int blk = blockIdx.x;
  const int t = threadIdx.x;
  if (blk < 1536) {
    int idx = blk*256 + t;   // 6*512*128 = 393216
    int m = idx & 127;
    int n = (idx>>7) & 511;
    int lq = idx >> 16;
    int l = lq>>1, qk = lq&1;
    size_t base = (((size_t)(lq*8 + (n>>6)))*64 + (n&63))*128 + m;
    float v = 0.f;
    #pragma unroll
    for (int ks=0;ks<8;++ks) v += effpart[(size_t)ks*393216 + base];
    wqkvT[((size_t)l*1536 + qk*512 + n)*128 + m] = f2bf(v);
  } else if (blk < 1662) {
    const int b2 = blk - 1536;   // 0..125
    if (b2 < 108) {
      __shared__ float tile[64][65];
      const float* src; unsigned short* dst; int srcld, dstld;
      if (b2 < 48) {
        int lay = b2/16, rem = b2%16, kt = rem>>3, nt = rem&7;
        src = wv + ((size_t)lay*128 + kt*64)*512 + nt*64; srcld = 512;
        dst = wqkvT + ((size_t)lay*1536 + 1024 + nt*64)*128 + kt*64; dstld = 128;
      } else if (b2 < 96) {
        int b3 = b2-48; int lay = b3/16, rem = b3%16, kt = rem>>1, nt = rem&1;
        src = out_w + ((size_t)lay*512 + kt*64)*128 + nt*64; srcld = 128;
        dst = outT + ((size_t)lay*128 + nt*64)*512 + kt*64; dstld = 512;
      } else {
        int b4 = b2-96; int lay = b4/4, rem = b4%4, kt = rem>>1, nt = rem&1;
        src = ffn_w + ((size_t)lay*128 + kt*64)*128 + nt*64; srcld = 128;
        dst = ffnT + ((size_t)lay*128 + nt*64)*128 + kt*64; dstld = 128;
      }
      #pragma unroll
      for (int rp=0; rp<4; ++rp){
        int r = rp*16 + (t>>4), c = (t&15)*4;
        float4 v = *(const float4*)(src + (size_t)r*srcld + c);
        tile[r][c+0]=v.x; tile[r][c+1]=v.y; tile[r][c+2]=v.z; tile[r][c+3]=v.w;
      }
      __syncthreads();
      #pragma unroll
      for (int wp=0; wp<2; ++wp){
        int n = wp*32 + (t>>3), kk = (t&7)*8;
        us8v pk;
        #pragma unroll
        for (int e=0;e<8;++e) pk[e] = f2bf(tile[kk+e][n]);
        *(us8v*)(dst + (size_t)n*dstld + kk) = pk;
      }
    } else {
      int idx = (b2-108)*256 + t;          // 0..4607
      if (idx < 4608) {
        int l = idx/1536, n = idx - l*1536;
        float v;
        if (n < 1024) {
          int qk = n>>9, c = n&511;
          v = inproj_b[(size_t)l*1536 + n];
          #pragma unroll
          for (int kt=0;kt<8;++kt) v += bpart[((l*2+qk)*8+kt)*512 + c];
        } else {
          v = bvv[(size_t)l*512 + (n-1024)];
        }
        bqkv[idx] = v;
      }
    }
  } else if (blk < 1674) {
    if (t < 128) {
      int p = blk - 1662, e = t;
      if (p < 10) {
        float Cp = 0.f;
        for (int ff=0; ff<10; ++ff){
          int f = p*10+ff;
          float A=0.f, Bv=0.f;
          #pragma unroll
          for (int s=0;s<10;++s){
            float wvv = emb_w[(size_t)(f*10+s)*128 + e];
            A += wvv; Bv += 0.2f*s*wvv; Cp += 0.01f*(s*s)*wvv;
          }
          int kA = 92+f, kB = 192+f;
          unsigned short hA = f2bf(A);
          WHi[e*320+kA]=hA; WLo[e*320+kA]=f2bf(A - bf2f(hA));
          unsigned short hB = f2bf(Bv);
          WHi[e*320+kB]=hB; WLo[e*320+kB]=f2bf(Bv - bf2f(hB));
        }
        Cpart[p*128+e] = Cp;
      } else if (p == 10) {
        for (int kk=0;kk<92;++kk){
          float v = comp_w[(size_t)kk*128 + e];
          unsigned short h = f2bf(v);
          WHi[e*320+kk]=h; WLo[e*320+kk]=f2bf(v - bf2f(h));
        }
      } else {
        for (int kk=292;kk<320;++kk){ WHi[e*320+kk]=0; WLo[e*320+kk]=0; }
      }
    }
  } else {
    int g = (blk-1674)*256 + t;      // M*40 = 655360
    int row = g / 40, seg = g - row*40;
    const float* sr = str_fea + (size_t)row*F_;
    if (seg == 0) w_row[row] = sr[0];
    const float* af = af_table + (size_t)comp_fea[row]*92;
    const int c0 = seg*8;
    us8v hi, lo;
    #pragma unroll
    for (int e=0;e<8;++e){
      int kk = c0+e; float v;
      if (kk < 92) v = af[kk];
      else if (kk < 192) { float u = 1.f - sr[1+kk-92]; v = u*u; }
      else if (kk < 292) v = 1.f - sr[1+kk-192];
      else v = 0.f;
      unsigned short h = f2bf(v);
      hi[e] = h; lo[e] = f2bf(v - bf2f(h));
    }
    *(us8v*)(FHi + (size_t)row*320 + c0) = hi;
    *(us8v*)(FLo + (size_t)row*320 + c0) = lo;
  }
}

// ---------- embed GEMM (split bf16, 3-MFMA) + inline biasE + LN0 epilogue ----------
__global__ __launch_bounds__(256) void embgemm_kernel(
    const unsigned short* __restrict__ FHi, const unsigned short* __restrict__ FLo,
    const unsigned short* __restrict__ WHi, const unsigned short* __restrict__ WLo,
    const float* __restrict__ Cpart, const float* __restrict__ comp_b,
    const float* __restrict__ emb_b,
    const float* __restrict__ g0, const float* __restrict__ b0,
    float* __restrict__ x, float* __restrict__ x_init,
    unsigned short* __restrict__ xnb) {
  __shared__ unsigned short lds[24576];    // 48 KB
  unsigned short* AHi = lds;
  unsigned short* ALo = lds + 4096;
  unsigned short* BHi = lds + 8192;
  unsigned short* BLo = lds + 16384;
  const int bm = blockIdx.x*64;
  const int t = threadIdx.x, w = t>>6, l = t&63;
  f4v acc[8];
  #pragma unroll
  for (int i=0;i<8;++i) acc[i] = (f4v){0.f,0.f,0.f,0.f};
  const int srow = t>>3, sseg = t&7;
  for (int k0=0;k0<320;k0+=64){
    #pragma unroll
    for (int c=0;c<2;++c){
      int row = c*32+srow;
      GLOAD16(FHi + (size_t)(bm+row)*320 + k0 + ((sseg^(row&7))<<3), (char*)AHi + c*4096 + w*1024);
      GLOAD16(FLo + (size_t)(bm+row)*320 + k0 + ((sseg^(row&7))<<3), (char*)ALo + c*4096 + w*1024);
    }
    #pragma unroll
    for (int c=0;c<4;++c){
      int row = c*32+srow;
      GLOAD16(WHi + (size_t)row*320 + k0 + ((sseg^(row&7))<<3), (char*)BHi + c*4096 + w*1024);
      GLOAD16(WLo + (size_t)row*320 + k0 + ((sseg^(row&7))<<3), (char*)BLo + c*4096 + w*1024);
    }
    __syncthreads();
    #pragma unroll
    for (int ks=0;ks<2;++ks){
      int arow = w*16 + (l&15);
      int aswz = ((((l>>4)+ks*4) ^ (arow&7))<<4);
      s8v ah = *(const s8v*)((const char*)AHi + arow*128 + aswz);
      s8v al = *(const s8v*)((const char*)ALo + arow*128 + aswz);
      #pragma unroll
      for (int ct=0;ct<8;++ct){
        int col = ct*16 + (l&15);
        int bswz = ((((l>>4)+ks*4) ^ (col&7))<<4);
        s8v bh = *(const s8v*)((const char*)BHi + col*128 + bswz);
        s8v bl = *(const s8v*)((const char*)BLo + col*128 + bswz);
        acc[ct] = MFMA16(ah, bh, acc[ct]);
        acc[ct] = MFMA16(ah, bl, acc[ct]);
        acc[ct] = MFMA16(al, bh, acc[ct]);
      }
    }
    __syncthreads();
  }
  float vv[8][4], gc[8], bc[8];
  #pragma unroll
  for (int ct=0;ct<8;++ct){
    int c = ct*16 + (l&15);
    float be = comp_b[c] + emb_b[c];
    for (int p=0;p<10;++p) be += Cpart[p*128+c];
    gc[ct] = g0[c]; bc[ct] = b0[c];
    #pragma unroll
    for (int r=0;r<4;++r) vv[ct][r] = acc[ct][r] + be;
  }
  #pragma unroll
  for (int r=0;r<4;++r){
    float s=0.f, sq=0.f;
    #pragma unroll
    for (int ct=0;ct<8;++ct){ s += vv[ct][r]; sq += vv[ct][r]*vv[ct][r]; }
    #pragma unroll
    for (int m=1;m<16;m<<=1){ s += __shfl_xor(s,m,64); sq += __shfl_xor(sq,m,64); }
    float mean = s*(1.f/128.f);
    float rstd = rsqrtf(sq*(1.f/128.f) - mean*mean + 1e-5f);
    int row = bm + w*16 + (l>>4)*4 + r;
    #pragma unroll
    for (int ct=0;ct<8;++ct){
      int c = ct*16 + (l&15);
      float v = vv[ct][r];
      x[(size_t)row*128 + c] = v;
      x_init[(size_t)row*128 + c] = v;
      xnb[(size_t)row*128 + c] = f2bf((v-mean)*rstd*gc[ct] + bc[ct]);
    }
  }
}

// ---------- bf16 MFMA GEMM (qkv): bf16 out -> qkb (n<1024) or transposed vT ----------
template<int RT>
__global__ __launch_bounds__(256) void mgemm_kernel(
    const unsigned short* __restrict__ A,
    const unsigned short* __restrict__ Bt,
    const float* __restrict__ bias,
    unsigned short* __restrict__ Cb,
    unsigned short* __restrict__ vT,
    int K) {
  constexpr int BM = RT*32;
  __shared__ float smem[8192];   // 32 KB
  unsigned short* Al = (unsigned short*)smem;
  unsigned short* Bl = Al + BM*64;
  const int bm = blockIdx.x*BM;
  const int bn = blockIdx.y*128;
  const int t = threadIdx.x;
  const int w = t>>6, l = t&63;
  const int wr = w>>1, wc = w&1;
  f4v acc[RT][4];
  #pragma unroll
  for (int i=0;i<RT;++i)
    #pragma unroll
    for (int j=0;j<4;++j) acc[i][j] = (f4v){0.f,0.f,0.f,0.f};
  const int srow = t>>3, sseg = t&7;
  for (int k0 = 0; k0 < K; k0 += 64) {
    #pragma unroll
    for (int c=0;c<BM/32;++c){
      int row = c*32 + srow;
      GLOAD16(A + (size_t)(bm+row)*K + k0 + ((sseg ^ (row&7))<<3),
              (char*)Al + c*4096 + w*1024);
    }
    #pragma unroll
    for (int c=0;c<4;++c){
      int row = c*32 + srow;
      GLOAD16(Bt + (size_t)(bn+row)*K + k0 + ((sseg ^ (row&7))<<3),
              (char*)Bl + c*4096 + w*1024);
    }
    __syncthreads();
    #pragma unroll
    for (int ks=0;ks<2;++ks){
      s8v bf[4];
      #pragma unroll
      for (int ct=0;ct<4;++ct){
        int col = wc*64 + ct*16 + (l&15);
        bf[ct] = *(const s8v*)((const char*)Bl + col*128 + ((((l>>4)+ks*4) ^ (col&7))<<4));
      }
      #pragma unroll
      for (int rt=0;rt<RT;++rt){
        int arow = wr*(RT*16) + rt*16 + (l&15);
        s8v af = *(const s8v*)((const char*)Al + arow*128 + ((((l>>4)+ks*4) ^ (arow&7))<<4));
        #pragma unroll
        for (int ct=0;ct<4;++ct)
          acc[rt][ct] = MFMA16(af, bf[ct], acc[rt][ct]);
      }
    }
    __syncthreads();
  }
  float bia[4];
  #pragma unroll
  for (int ct=0;ct<4;++ct) bia[ct] = bias[bn + wc*64 + ct*16 + (l&15)];
  unsigned short* lds16 = (unsigned short*)smem;
  if (bn < 1024) {
    #pragma unroll
    for (int rt=0;rt<RT;++rt)
      #pragma unroll
      for (int ct=0;ct<4;++ct)
        #pragma unroll
        for (int r=0;r<4;++r){
          int rr = wr*(RT*16) + rt*16 + (l>>4)*4 + r;
          int cc = wc*64 + ct*16 + (l&15);
          lds16[rr*128 + cc] = f2bf(acc[rt][ct][r] + bia[ct]);
        }
    __syncthreads();
    #pragma unroll
    for (int it=0; it<BM/16; ++it){
      int row = it*16 + (t>>4), seg = t&15;
      u4v v = *(const u4v*)(lds16 + row*128 + seg*8);
      *(u4v*)(Cb + (size_t)(bm+row)*1024 + bn + seg*8) = v;
    }
  } else {
    #pragma unroll
    for (int rt=0;rt<RT;++rt)
      #pragma unroll
      for (int ct=0;ct<4;++ct){
        int rbase = bm + wr*(RT*16) + rt*16 + (l>>4)*4;
        int bb = rbase >> 9, nn = rbase & 511;
        int d = bn - 1024 + wc*64 + ct*16 + (l&15);
        unsigned int lo = (unsigned int)f2bf(acc[rt][ct][0] + bia[ct])
                        | ((unsigned int)f2bf(acc[rt][ct][1] + bia[ct])<<16);
        unsigned int hi = (unsigned int)f2bf(acc[rt][ct][2] + bia[ct])
                        | ((unsigned int)f2bf(acc[rt][ct][3] + bia[ct])<<16);
        uint2 pk; pk.x = lo; pk.y = hi;
        *(uint2*)(vT + ((size_t)(bb*512 + d))*512 + nn) = pk;
      }
  }
}

// ---------- fused attention (single-QK) + tail, reduced barriers + setprio ----------
#define STG_KH(dst, hh, j0s) { \
  _Pragma("unroll") \
  for (int c_=0;c_<8;++c_){ \
    int row_ = c_*32 + w*4 + (l>>4); \
    GLOAD16(qkb + (size_t)(b*512 + (j0s) + row_)*1024 + 512 + (hh)*128 + (((l&15) ^ (row_&7))<<3), \
            (dst) + c_*8192 + w*1024); } }

#define STG_VT(dst, j0s) { \
  _Pragma("unroll") \
  for (int c_=0;c_<4;++c_){ \
    int d_ = c_*128 + w*16 + (l>>2); \
    GLOAD16(vT + ((size_t)(b*512 + d_))*512 + (j0s) + (((l&3) ^ ((d_>>1)&3))<<3), \
            (dst) + c_*8192 + w*1024); } }

// stage 128-k chunk of outT [128n][512k] into dst[128n][256B], swizzled
#define STG_B2(dst, k0s) { \
  _Pragma("unroll") \
  for (int c_=0;c_<4;++c_){ \
    int n_ = c_*32 + w*4 + (l>>4); \
    GLOAD16(outTl + (size_t)n_*512 + (k0s) + (((l&15) ^ (n_&7))<<3), \
            (dst) + (c_*32 + w*4)*256); } }

// stage ffnT [128n][128k] into ffnB two 64-k halves
#define STG_F1() { \
  _Pragma("unroll") \
  for (int c2_=0;c2_<4;++c2_){ \
    int kh_ = c2_>>1, c_ = c2_&1; \
    int n_ = c_*64 + w*8 + (l>>3); \
    GLOAD16(ffnTl + (size_t)n_*128 + kh_*64 + (((l&7) ^ (n_&7))<<3), \
            ffnB + kh_*16384 + (c_*64 + w*8)*128); } }

__global__ __launch_bounds__(512, 2) void attnX_kernel(
    const unsigned short* __restrict__ qkb, const unsigned short* __restrict__ vT,
    const float* __restrict__ w_row,
    const unsigned short* __restrict__ outTl, const float* __restrict__ out_b,
    const unsigned short* __restrict__ ffnTl, const float* __restrict__ ffn_b,
    float* __restrict__ x, unsigned short* __restrict__ xnb,
    const float* __restrict__ g1, const float* __restrict__ b1,
    const float* __restrict__ g2, const float* __restrict__ b2) {
  __shared__ char smem[136704];
  // QK phase: K dbuf [0,131072)
  char* const Kt0 = smem;
  char* const Kt1 = smem + 65536;
  // combine/PV phase: cAL [64][520] bf16 at [0,66560), V dbuf
  char* const cALc = smem;
  unsigned short* const cAL = (unsigned short*)smem;
  char* const VbA = smem + 66560;               // 32 KB
  char* const VbB = smem + 99328;               // 32 KB
  float* const w_s    = (float*)(smem + 132096); // 512 f32
  float* const Spart  = (float*)(smem + 134144); // [2][64]
  float* const Rpart  = (float*)(smem + 134656); // [2][64]
  float* const rho_l  = (float*)(smem + 135424); // [4][64]
  float* const zinv_l = (float*)(smem + 136448); // [64]
  // tail phase
  unsigned short* const outL = (unsigned short*)smem;  // [64][520]
  char* const BtA = smem + 66560;               // 32 KB (128k B tile)
  char* const BtB = smem + 99328;               // 32 KB
  float* const vst = (float*)(smem + 66560);    // 32 KB, overlays dead BtA
  char* const xnl  = smem;                      // 16 KB over dead outL
  char* const ffnB = smem + 16384;              // 32 KB over dead outL

  const int id = blockIdx.x;
  const int b  = (id & 7) | ((id >> 6) << 3);
  const int i0 = ((id >> 3) & 7) * 64;
  const int bm = b*512 + i0;
  const int t = threadIdx.x, w = t>>6, l = t&63;
  const int wi = w & 3, wd = w >> 2;
  const int ib = wi*16 + (l>>4)*4;
  const int arow = wi*16 + (l&15);
  const float SC2 = 1.4426950408889634f * 0.088388347648318447f; // log2e/sqrt(128)

  for (int j=t; j<512; j+=512) w_s[j] = w_row[b*512+j];

  float c_[2][8][4];
  #pragma unroll
  for (int tt=0;tt<2;++tt)
    #pragma unroll
    for (int js=0;js<8;++js)
      #pragma unroll
      for (int r=0;r<4;++r) c_[tt][js][r] = 0.f;

  STG_KH(Kt0, 0, 0);
  __syncthreads();   // w_s ready + first K tile landed

  char* Kc = Kt0; char* Kn = Kt1;
  #pragma unroll 1
  for (int h=0; h<4; ++h){
    s8v qf[4];
    {
      const unsigned short* qbase = qkb + ((size_t)(bm + arow))*1024 + h*128;
      #pragma unroll
      for (int ks=0;ks<4;++ks) qf[ks] = *(const s8v*)(qbase + ks*32 + (l>>4)*8);
    }
    float Ex[2][8][4];
    #pragma unroll
    for (int tt=0; tt<2; ++tt){
      if (tt==0) { STG_KH(Kn, h, 256); }
      else if (h<3) { STG_KH(Kn, h+1, 0); }
      __builtin_amdgcn_s_setprio(1);
      #pragma unroll
      for (int jsub=0;jsub<8;++jsub){
        const int jcol = wd*128 + jsub*16 + (l&15);
        f4v a = (f4v){0.f,0.f,0.f,0.f};
        #pragma unroll
        for (int ks=0;ks<4;++ks){
          int g = ks*4 + (l>>4);
          s8v kf = *(const s8v*)(Kc + jcol*256 + ((g ^ (jcol&7))<<4));
          a = MFMA16(qf[ks], kf, a);
        }
        #pragma unroll
        for (int r=0;r<4;++r) Ex[tt][jsub][r] = exp2f(a[r]*SC2);
      }
      __builtin_amdgcn_s_setprio(0);
      __syncthreads();   // staged load aged through compute; Kc reads done
      char* tmp = Kc; Kc = Kn; Kn = tmp;
    }
    // S_h, rho_h reduction
    float sp[4] = {0.f,0.f,0.f,0.f};
    float rp[4] = {0.f,0.f,0.f,0.f};
    #pragma unroll
    for (int tt=0;tt<2;++tt)
      #pragma unroll
      for (int jsub=0;jsub<8;++jsub){
        int jg = tt*256 + wd*128 + jsub*16 + (l&15);
        float wv = w_s[jg];
        float mw = (wv != 0.f) ? 1.f : 0.f;
        #pragma unroll
        for (int r=0;r<4;++r){
          sp[r] += Ex[tt][jsub][r]*mw;
          rp[r] += Ex[tt][jsub][r]*wv;
        }
      }
    #pragma unroll
    for (int r=0;r<4;++r){
      float s = sp[r], rv = rp[r];
      s += __shfl_xor(s,1,64); rv += __shfl_xor(rv,1,64);
      s += __shfl_xor(s,2,64); rv += __shfl_xor(rv,2,64);
      s += __shfl_xor(s,4,64); rv += __shfl_xor(rv,4,64);
      s += __shfl_xor(s,8,64); rv += __shfl_xor(rv,8,64);
      sp[r] = s; rp[r] = rv;
    }
    if ((l&15)==0){
      #pragma unroll
      for (int r=0;r<4;++r){
        Spart[wd*64 + ib + r] = sp[r];
        Rpart[wd*64 + ib + r] = rp[r];
      }
    }
    __syncthreads();   // Spart/Rpart visible (single barrier)
    if (t < 64){
      float S0 = Spart[t] + Spart[64+t];
      float R = Rpart[t] + Rpart[64+t];
      rho_l[h*64+t] = R/S0;          // same-thread read at zinv time: no barrier needed
    }
    float siv[4];
    #pragma unroll
    for (int r=0;r<4;++r)
      siv[r] = 1.f/(Spart[ib + r] + Spart[64 + ib + r]);
    #pragma unroll
    for (int tt=0;tt<2;++tt)
      #pragma unroll
      for (int jsub=0;jsub<8;++jsub)
        #pragma unroll
        for (int r=0;r<4;++r)
          c_[tt][jsub][r] += Ex[tt][jsub][r]*siv[r];
  }

  // K region dead. Prefetch V0; compute zinv; write cw tile to cAL.
  __syncthreads();   // Spart reads (all threads) complete before region reuse below
  STG_VT(VbA, 0);
  if (t < 64)
    zinv_l[t] = 1.f/(rho_l[t] + rho_l[64+t] + rho_l[128+t] + rho_l[192+t]);
  #pragma unroll
  for (int tt=0;tt<2;++tt)
    #pragma unroll
    for (int jsub=0;jsub<8;++jsub){
      int jg = tt*256 + wd*128 + jsub*16 + (l&15);
      float wv = w_s[jg];
      #pragma unroll
      for (int r=0;r<4;++r)
        cAL[(ib+r)*520 + jg] = f2bf(c_[tt][jsub][r]*wv);
    }
  __syncthreads();   // V0 drained; cAL + zinv visible
  float zv[4][4];
  #pragma unroll
  for (int ig=0;ig<4;++ig)
    #pragma unroll
    for (int r=0;r<4;++r) zv[ig][r] = zinv_l[ig*16 + (l>>4)*4 + r];

  // ---- PV: 16 V tiles of 32 j; wave owns d-slice w*64..w*64+64; af/vf reused 4x ----
  f4v pacc[4][4];   // [ig][dsub]
  #pragma unroll
  for (int ig=0;ig<4;++ig)
    #pragma unroll
    for (int ds=0;ds<4;++ds) pacc[ig][ds] = (f4v){0.f,0.f,0.f,0.f};
  {
    char* Vc = VbA; char* Vn = VbB;
    #pragma unroll 1
    for (int vt=0; vt<16; ++vt){
      if (vt < 15) STG_VT(Vn, (vt+1)*32);
      int kidx = l>>4;
      s8v af[4];
      #pragma unroll
      for (int ig=0;ig<4;++ig)
        af[ig] = *(const s8v*)(cALc + (ig*16 + (l&15))*1040 + vt*64 + (kidx<<4));
      __builtin_amdgcn_s_setprio(1);
      #pragma unroll
      for (int dsub=0;dsub<4;++dsub){
        int d = w*64 + dsub*16 + (l&15);
        s8v vf = *(const s8v*)(Vc + d*64 + ((kidx ^ ((d>>1)&3))<<4));
        #pragma unroll
        for (int ig=0;ig<4;++ig)
          pacc[ig][dsub] = MFMA16(af[ig], vf, pacc[ig][dsub]);
      }
      __builtin_amdgcn_s_setprio(0);
      __syncthreads();   // Vc reads done; staged load drained
      char* tmp = Vc; Vc = Vn; Vn = tmp;
    }
  }

  // ---- write scaled att tile to outL (bf16, [64][520]) ----
  #pragma unroll
  for (int ig=0;ig<4;++ig)
    #pragma unroll
    for (int dsub=0;dsub<4;++dsub){
      int d = w*64 + dsub*16 + (l&15);
      #pragma unroll
      for (int r=0;r<4;++r)
        outL[(ig*16 + (l>>4)*4 + r)*520 + d] = f2bf(pacc[ig][dsub][r]*zv[ig][r]);
    }
  STG_B2(BtA, 0);        // prologue out-proj B tile (128k)
  __syncthreads();

  // ---- GEMM1: o1 = att(outL) @ outT^T, 4 phases of 128k ----
  f4v acc1[4];
  #pragma unroll
  for (int ct=0;ct<4;++ct) acc1[ct] = (f4v){0.f,0.f,0.f,0.f};
  {
    char* Bc = BtA; char* Bn = BtB;
    #pragma unroll 1
    for (int tt=0; tt<4; ++tt){
      if (tt < 3) STG_B2(Bn, (tt+1)*128);
      __builtin_amdgcn_s_setprio(1);
      #pragma unroll
      for (int ks=0;ks<4;++ks){
        int kidx = (l>>4) + ks*4;
        s8v af = *(const s8v*)((const char*)outL + arow*1040 + tt*256 + (kidx<<4));
        #pragma unroll
        for (int ct=0;ct<4;++ct){
          int n = wd*64 + ct*16 + (l&15);
          s8v bf = *(const s8v*)(Bc + n*256 + ((kidx ^ (n&7))<<4));
          acc1[ct] = MFMA16(af, bf, acc1[ct]);
        }
      }
      __builtin_amdgcn_s_setprio(0);
      __syncthreads();
      char* tmp = Bc; Bc = Bn; Bn = tmp;
    }
  }

  // epilogue1: o1 = acc1 + out_b + x -> vst (overlays dead BtA) ; stage ffnB
  #pragma unroll
  for (int ct=0;ct<4;++ct){
    int cc = wd*64 + ct*16 + (l&15);
    float ob = out_b[cc];
    #pragma unroll
    for (int r=0;r<4;++r){
      int rr = wi*16 + (l>>4)*4 + r;
      vst[rr*128 + cc] = acc1[ct][r] + ob + x[(size_t)(bm+rr)*128 + cc];
    }
  }
  STG_F1();
  __syncthreads();

  // LN1 -> xnl (swizzled bf16 A-layout), 8 rows per wave
  {
    const float2 g1v = *(const float2*)(g1 + l*2);
    const float2 b1v = *(const float2*)(b1 + l*2);
    #pragma unroll
    for (int rr=0; rr<8; ++rr){
      int row = w*8 + rr;
      float2 vv = *(const float2*)&vst[row*128 + l*2];
      float s = vv.x+vv.y, sq = vv.x*vv.x + vv.y*vv.y;
      #pragma unroll
      for (int m=1;m<64;m<<=1){ s += __shfl_xor(s,m,64); sq += __shfl_xor(sq,m,64); }
      float mean = s*(1.f/128.f);
      float rstd = rsqrtf(sq*(1.f/128.f) - mean*mean + 1e-5f);
      float xa = (vv.x-mean)*rstd*g1v.x + b1v.x;
      float xb = (vv.y-mean)*rstd*g1v.y + b1v.y;
      int col = l*2;
      int byte = row*256 + (((col>>3) ^ (row&7))<<4) + ((col&7)<<1);
      unsigned int pk = (unsigned int)f2bf(xa) | ((unsigned int)f2bf(xb)<<16);
      *(unsigned int*)(xnl + byte) = pk;
    }
  }
  __syncthreads();   // xnl visible; ffnB drained

  // GEMM2: o2 = xn @ ffnT^T, per wave 16i x 64e
  f4v acc2[4];
  #pragma unroll
  for (int ct=0;ct<4;++ct) acc2[ct] = (f4v){0.f,0.f,0.f,0.f};
  __builtin_amdgcn_s_setprio(1);
  #pragma unroll
  for (int ks2=0;ks2<4;++ks2){
    int kidx2 = (l>>4) + ks2*4;
    s8v af = *(const s8v*)(xnl + arow*256 + ((kidx2 ^ (arow&7))<<4));
    int kh = ks2>>1, ksb = ks2&1;
    int kb = (l>>4) + ksb*4;
    #pragma unroll
    for (int ct=0;ct<4;++ct){
      int n = wd*64 + ct*16 + (l&15);
      s8v bf = *(const s8v*)(ffnB + kh*16384 + n*128 + ((kb ^ (n&7))<<4));
      acc2[ct] = MFMA16(af, bf, acc2[ct]);
    }
  }
  __builtin_amdgcn_s_setprio(0);
  // epilogue2: vst += softplus(acc2 + ffn_b)
  #pragma unroll
  for (int ct=0;ct<4;++ct){
    int cc = wd*64 + ct*16 + (l&15);
    float fb = ffn_b[cc];
    #pragma unroll
    for (int r=0;r<4;++r){
      int rr = wi*16 + (l>>4)*4 + r;
      vst[rr*128 + cc] += softplus_f(acc2[ct][r] + fb);
    }
  }
  __syncthreads();

  // LN2 -> x ; optional LN3 -> xnb
  {
    const float2 g1v = *(const float2*)(g1 + l*2);
    const float2 b1v = *(const float2*)(b1 + l*2);
    #pragma unroll
    for (int rr=0; rr<8; ++rr){
      int row = w*8 + rr;
      float2 vv = *(const float2*)&vst[row*128 + l*2];
      float s = vv.x+vv.y, sq = vv.x*vv.x + vv.y*vv.y;
      #pragma unroll
      for (int m=1;m<64;m<<=1){ s += __shfl_xor(s,m,64); sq += __shfl_xor(sq,m,64); }
      float mean = s*(1.f/128.f);
      float rstd = rsqrtf(sq*(1.f/128.f) - mean*mean + 1e-5f);
      float xa = (vv.x-mean)*rstd*g1v.x + b1v.x;
      float xb = (vv.y-mean)*rstd*g1v.y + b1v.y;
      float2 xo; xo.x = xa; xo.y = xb;
      *(float2*)(x + (size_t)(bm+row)*128 + l*2) = xo;
      if (g2) {
        float s2 = xa+xb, sq2 = xa*xa + xb*xb;
        #pragma unroll
        for (int m=1;m<64;m<<=1){ s2 += __shfl_xor(s2,m,64); sq2 += __shfl_xor(sq2,m,64); }
        float mean2 = s2*(1.f/128.f);
        float rstd2 = rsqrtf(sq2*(1.f/128.f) - mean2*mean2 + 1e-5f);
        const float2 g2v = *(const float2*)(g2 + l*2);
        const float2 b2v = *(const float2*)(b2 + l*2);
        float ya = (xa-mean2)*rstd2*g2v.x + b2v.x;
        float yb = (xb-mean2)*rstd2*g2v.y + b2v.y;
        unsigned int pk = (unsigned int)f2bf(ya) | ((unsigned int)f2bf(yb)<<16);
        *(unsigned int*)(xnb + (size_t)(bm+row)*128 + l*2) = pk;
      }
    }
  }
}

// ---------- fused pooling + final (one dispatch) ----------
__global__ __launch_bounds__(256) void poolfinal_kernel(
    const float* __restrict__ x, const float* __restrict__ x_init,
    const float* __restrict__ w_row,
    const float* __restrict__ g, const float* __restrict__ bt,
    const float* __restrict__ fw, const float* __restrict__ fb,
    float* __restrict__ out) {
  __shared__ float red[2][128];
  __shared__ float red2[4];
  __shared__ float red3[2];
  const int b = blockIdx.x;
  const int t = threadIdx.x;
  const int e = t & 127, half = t >> 7;
  float acc = 0.f;
  for (int n = half*256; n < half*256+256; ++n) {
    float w = w_row[(size_t)b*N_ + n];
    size_t o = ((size_t)b*N_ + n)*E_ + e;
    acc += w * (x[o] + x_init[o]);
  }
  red[half][e] = acc;
  __syncthreads();
  float s=0.f, sq=0.f, v=0.f;
  if (t < 128) {
    v = red[0][t] + red[1][t];
    s = v; sq = v*v;
    #pragma unroll
    for (int m = 1; m < 64; m <<= 1) { s += __shfl_xor(s, m, 64); sq += __shfl_xor(sq, m, 64); }
    if ((t&63) == 0) { red2[(t>>6)*2] = s; red2[(t>>6)*2+1] = sq; }
  }
  __syncthreads();
  float p = 0.f;
  if (t < 128) {
    s = red2[0] + red2[2]; sq = red2[1] + red2[3];
    float mean = s*(1.f/E_), var = sq*(1.f/E_) - mean*mean;
    float rstd = rsqrtf(var + 1e-5f);
    float xl = (v - mean)*rstd*g[t] + bt[t];
    p = xl * fw[t];
    #pragma unroll
    for (int m = 1; m < 64; m <<= 1) p += __shfl_xor(p, m, 64);
    if ((t&63) == 0) red3[t>>6] = p;
  }
  __syncthreads();
  if (t == 0) out[b] = red3[0] + red3[1] + fb[0];
}

extern "C" void kernel_launch(void* const* d_in, const int* in_sizes, int n_in,
                              void* d_out, int out_size, void* d_ws, size_t ws_size,
                              hipStream_t stream) {
  (void)in_sizes; (void)n_in; (void)out_size; (void)ws_size;
  const float* str_fea  = (const float*)d_in[0];
  const int*   comp_fea = (const int*)  d_in[1];
  const float* af_table = (const float*)d_in[3];
  const float* comp_w   = (const float*)d_in[4];
  const float* comp_b   = (const float*)d_in[5];
  const float* emb_w    = (const float*)d_in[6];
  const float* emb_b    = (const float*)d_in[7];
  const float* ln_g     = (const float*)d_in[8];
  const float* ln_b     = (const float*)d_in[9];
  const float* wq       = (const float*)d_in[10];
  const float* bq       = (const float*)d_in[11];
  const float* wk       = (const float*)d_in[12];
  const float* bk       = (const float*)d_in[13];
  const float* wv       = (const float*)d_in[14];
  const float* bv       = (const float*)d_in[15];
  const float* inproj_w = (const float*)d_in[16];
  const float* inproj_b = (const float*)d_in[17];
  const float* out_w    = (const float*)d_in[18];
  const float* out_b    = (const float*)d_in[19];
  const float* ffn_w    = (const float*)d_in[20];
  const float* ffn_b    = (const float*)d_in[21];
  const float* ln2_g    = (const float*)d_in[22];
  const float* ln2_b    = (const float*)d_in[23];
  const float* final_w  = (const float*)d_in[24];
  const float* final_b  = (const float*)d_in[25];
  float* out = (float*)d_out;

  float* ws = (float*)d_ws;
  size_t off = 0;
  float* x      = ws + off; off += 2097152;
  float* x_init = ws + off; off += 2097152;
  float* w_row  = ws + off; off += 16384;
  unsigned short* xnb  = (unsigned short*)(ws + off); off += 1048576;   // [M][128]
  unsigned short* qkb  = (unsigned short*)(ws + off); off += 8388608;   // [M][1024]
  unsigned short* vTb  = (unsigned short*)(ws + off); off += 4194304;   // [B][512][512]
  float* bpart  = ws + off; off += 24576;    // [6][8][512]
  float* effpart= ws + off; off += 3145728;  // [8][6][8][64][128] f32
  float* bqkv   = ws + off; off += 4608;
  unsigned short* wqkvT = (unsigned short*)(ws + off); off += 294912;   // [3][1536][128]
  unsigned short* outT  = (unsigned short*)(ws + off); off += 98304;    // [3][128][512]
  unsigned short* ffnT  = (unsigned short*)(ws + off); off += 24576;    // [3][128][128]
  unsigned short* FHi   = (unsigned short*)(ws + off); off += 2621440;  // [M][320]
  unsigned short* FLo   = (unsigned short*)(ws + off); off += 2621440;
  unsigned short* WHi   = (unsigned short*)(ws + off); off += 20480;    // [128][320]
  unsigned short* WLo   = (unsigned short*)(ws + off); off += 20480;
  float* Cpart  = ws + off; off += 1280;

  prepA_kernel<<<432, 256, 0, stream>>>(wq, wk, bq, bk, inproj_w, effpart, bpart);
  prepB_kernel<<<4234, 256, 0, stream>>>(effpart, bpart, wv, out_w, ffn_w,
                                         inproj_b, bv, emb_w, comp_w,
                                         str_fea, comp_fea, af_table,
                                         wqkvT, outT, ffnT, bqkv,
                                         WHi, WLo, Cpart, FHi, FLo, w_row);
  embgemm_kernel<<<M_/64, 256, 0, stream>>>(FHi, FLo, WHi, WLo, Cpart, comp_b, emb_b,
                                            ln_g, ln_b, x, x_init, xnb);

  for (int l = 0; l < L_; ++l) {
    mgemm_kernel<4><<<dim3(M_/128, 12), 256, 0, stream>>>(
        xnb, wqkvT + (size_t)l*196608, bqkv + l*1536, qkb, vTb, 128);
    attnX_kernel<<<256, 512, 0, stream>>>(
        qkb, vTb, w_row,
        outT + (size_t)l*65536, out_b + (size_t)l*E_,
        ffnT + (size_t)l*16384, ffn_b + (size_t)l*E_,
        x, xnb, ln_g + l*E_, ln_b + l*E_,
        (l < 2) ? (ln_g + (l+1)*E_) : nullptr,
        (l < 2) ? (ln_b + (l+1)*E_) : nullptr);
  }

  poolfinal_kernel<<<B_, 256, 0, stream>>>(x, x_init, w_row, ln2_g, ln2_b,
                                           final_w, final_b, out);
}

// Round 20
// 300.901 us; speedup vs baseline: 1.0094x; 1.0094x over previous
//
#include <hip/hip_runtime.h>
#include <math.h>

#define B_ 32
#define N_ 512
#define F_ 101
#define E_ 128
#define H_ 4
#define EH_ 512
#define L_ 3
#define M_ (B_*N_)   // 16384

typedef __attribute__((ext_vector_type(8))) short s8v;
typedef __attribute__((ext_vector_type(8))) unsigned short us8v;
typedef __attribute__((ext_vector_type(4))) float f4v;
typedef __attribute__((ext_vector_type(4))) unsigned int u4v;

__device__ __forceinline__ unsigned short f2bf(float f){
  unsigned int u = __builtin_bit_cast(unsigned int, f);
  u += 0x7fffu + ((u>>16)&1u);
  return (unsigned short)(u>>16);
}
__device__ __forceinline__ float bf2f(unsigned int h){
  unsigned int u = h<<16; return __builtin_bit_cast(float, u);
}
__device__ __forceinline__ float softplus_f(float v) {
  return fmaxf(v, 0.f) + log1pf(__expf(-fabsf(v)));
}

#define GLOAD16(gp, lp) __builtin_amdgcn_global_load_lds( \
    (__attribute__((address_space(1))) unsigned int*)(gp), \
    (__attribute__((address_space(3))) unsigned int*)(lp), 16, 0, 0)

#define MFMA16(a,b,c) __builtin_amdgcn_mfma_f32_16x16x32_bf16(a,b,c,0,0,0)

// ---------- prepA: effp (blk<384) + effb_part (blk>=384) ----------
__global__ __launch_bounds__(256) void prepA_kernel(
    const float* __restrict__ wq, const float* __restrict__ wk,
    const float* __restrict__ bq, const float* __restrict__ bk,
    const float* __restrict__ inproj_w,
    float* __restrict__ effpart, float* __restrict__ bpart) {
  __shared__ float As[64][132];   // [kk][r]
  __shared__ float Bs[64][68];    // [kk][c]
  const int blk = blockIdx.x;
  const int t = threadIdx.x;
  if (blk < 384) {
    const int bx = blk % 48, ks = blk / 48;
    const int lq = bx>>3, nt = bx&7;
    const int l = lq>>1, qk = lq&1;
    const int bn = nt*64;
    const int k0 = ks*64;
    const float* A = (qk ? wk : wq) + (size_t)l*128*512;
    const float* IP = inproj_w + (size_t)l*512*1536 + qk*512 + bn;
    float acc[8][4];
    #pragma unroll
    for (int i=0;i<8;++i)
      #pragma unroll
      for (int j=0;j<4;++j) acc[i][j]=0.f;
    const int r0 = (t&15)*8, c0 = (t>>4)*4;
    {
      int r = t & 127, half = t>>7;
      #pragma unroll
      for (int u=0;u<8;++u){
        float4 a = *(const float4*)(A + (size_t)r*512 + k0 + half*32 + u*4);
        int kk = half*32 + u*4;
        As[kk+0][r]=a.x; As[kk+1][r]=a.y; As[kk+2][r]=a.z; As[kk+3][r]=a.w;
      }
      int kk = t>>2, cb = (t&3)*16;
      #pragma unroll
      for (int u=0;u<4;++u)
        *(float4*)&Bs[kk][cb+u*4] = *(const float4*)(IP + (size_t)(k0+kk)*1536 + cb + u*4);
    }
    __syncthreads();
    for (int k2=0;k2<64;++k2){
      float4 b = *(const float4*)&Bs[k2][c0];
      float4 a0 = *(const float4*)&As[k2][r0];
      float4 a1 = *(const float4*)&As[k2][r0+4];
      float av[8] = {a0.x,a0.y,a0.z,a0.w,a1.x,a1.y,a1.z,a1.w};
      #pragma unroll
      for (int i=0;i<8;++i){
        acc[i][0] += av[i]*b.x; acc[i][1] += av[i]*b.y;
        acc[i][2] += av[i]*b.z; acc[i][3] += av[i]*b.w;
      }
    }
    #pragma unroll
    for (int j=0;j<4;++j){
      float* dst = effpart + (((size_t)ks*48 + bx)*64 + c0 + j)*128 + r0;
      float4 v0 = {acc[0][j], acc[1][j], acc[2][j], acc[3][j]};
      float4 v1 = {acc[4][j], acc[5][j], acc[6][j], acc[7][j]};
      *(float4*)dst = v0;
      *(float4*)(dst+4) = v1;
    }
  } else {
    const int idxb = blk - 384;           // 0..47
    const int lq = idxb>>3, kt = idxb&7;
    const int l = lq>>1, qk = lq&1;
    const float* bv = (qk?bk:bq) + l*512 + kt*64;
    const float* IP = inproj_w + ((size_t)l*512 + kt*64)*1536 + qk*512;
    float a0=0.f, a1=0.f;
    for (int kk=0; kk<64; ++kk){
      float b = bv[kk];
      const float* row = IP + (size_t)kk*1536;
      a0 += b*row[t];
      a1 += b*row[t+256];
    }
    bpart[(lq*8+kt)*512 + t]       = a0;
    bpart[(lq*8+kt)*512 + t + 256] = a1;
  }
}

// ---------- prepB: effred | wtrans+bqkv | embW1 | feat ----------
__global__ __launch_bounds__(256) void prepB_kernel(
    const float* __restrict__ effpart, const float* __restrict__ bpart,
    const float* __restrict__ wv, const float* __restrict__ out_w,
    const float* __restrict__ ffn_w,
    const float* __restrict__ inproj_b, const float* __restrict__ bvv,
    const float* __restrict__ emb_w, const float* __restrict__ comp_w,
    const float* __restrict__ str_fea, const int* __restrict__ comp_fea,
    const float* __restrict__ af_table,
    unsigned short* __restrict__ wqkvT, unsigned short* __restrict__ outT,
    unsigned short* __restrict__ ffnT, float* __restrict__ bqkv,
    unsigned short* __restrict__ WHi, unsigned short* __restrict__ WLo,
    float* __restrict__ Cpart,
    unsigned short* __restrict__ FHi, unsigned short* __restrict__ FLo,
    float* __restrict__ w_row) {
  const int blk = blockIdx.x;
  const int t = threadIdx.x;
  if (blk < 1536) {
    int idx = blk*256 + t;   // 6*512*128 = 393216
    int m = idx & 127;
    int n = (idx>>7) & 511;
    int lq = idx >> 16;
    int l = lq>>1, qk = lq&1;
    size_t base = (((size_t)(lq*8 + (n>>6)))*64 + (n&63))*128 + m;
    float v = 0.f;
    #pragma unroll
    for (int ks=0;ks<8;++ks) v += effpart[(size_t)ks*393216 + base];
    wqkvT[((size_t)l*1536 + qk*512 + n)*128 + m] = f2bf(v);
  } else if (blk < 1662) {
    const int b2 = blk - 1536;   // 0..125
    if (b2 < 108) {
      __shared__ float tile[64][65];
      const float* src; unsigned short* dst; int srcld, dstld;
      if (b2 < 48) {
        int lay = b2/16, rem = b2%16, kt = rem>>3, nt = rem&7;
        src = wv + ((size_t)lay*128 + kt*64)*512 + nt*64; srcld = 512;
        dst = wqkvT + ((size_t)lay*1536 + 1024 + nt*64)*128 + kt*64; dstld = 128;
      } else if (b2 < 96) {
        int b3 = b2-48; int lay = b3/16, rem = b3%16, kt = rem>>1, nt = rem&1;
        src = out_w + ((size_t)lay*512 + kt*64)*128 + nt*64; srcld = 128;
        dst = outT + ((size_t)lay*128 + nt*64)*512 + kt*64; dstld = 512;
      } else {
        int b4 = b2-96; int lay = b4/4, rem = b4%4, kt = rem>>1, nt = rem&1;
        src = ffn_w + ((size_t)lay*128 + kt*64)*128 + nt*64; srcld = 128;
        dst = ffnT + ((size_t)lay*128 + nt*64)*128 + kt*64; dstld = 128;
      }
      #pragma unroll
      for (int rp=0; rp<4; ++rp){
        int r = rp*16 + (t>>4), c = (t&15)*4;
        float4 v = *(const float4*)(src + (size_t)r*srcld + c);
        tile[r][c+0]=v.x; tile[r][c+1]=v.y; tile[r][c+2]=v.z; tile[r][c+3]=v.w;
      }
      __syncthreads();
      #pragma unroll
      for (int wp=0; wp<2; ++wp){
        int n = wp*32 + (t>>3), kk = (t&7)*8;
        us8v pk;
        #pragma unroll
        for (int e=0;e<8;++e) pk[e] = f2bf(tile[kk+e][n]);
        *(us8v*)(dst + (size_t)n*dstld + kk) = pk;
      }
    } else {
      int idx = (b2-108)*256 + t;          // 0..4607
      if (idx < 4608) {
        int l = idx/1536, n = idx - l*1536;
        float v;
        if (n < 1024) {
          int qk = n>>9, c = n&511;
          v = inproj_b[(size_t)l*1536 + n];
          #pragma unroll
          for (int kt=0;kt<8;++kt) v += bpart[((l*2+qk)*8+kt)*512 + c];
        } else {
          v = bvv[(size_t)l*512 + (n-1024)];
        }
        bqkv[idx] = v;
      }
    }
  } else if (blk < 1674) {
    if (t < 128) {
      int p = blk - 1662, e = t;
      if (p < 10) {
        float Cp = 0.f;
        for (int ff=0; ff<10; ++ff){
          int f = p*10+ff;
          float A=0.f, Bv=0.f;
          #pragma unroll
          for (int s=0;s<10;++s){
            float wvv = emb_w[(size_t)(f*10+s)*128 + e];
            A += wvv; Bv += 0.2f*s*wvv; Cp += 0.01f*(s*s)*wvv;
          }
          int kA = 92+f, kB = 192+f;
          unsigned short hA = f2bf(A);
          WHi[e*320+kA]=hA; WLo[e*320+kA]=f2bf(A - bf2f(hA));
          unsigned short hB = f2bf(Bv);
          WHi[e*320+kB]=hB; WLo[e*320+kB]=f2bf(Bv - bf2f(hB));
        }
        Cpart[p*128+e] = Cp;
      } else if (p == 10) {
        for (int kk=0;kk<92;++kk){
          float v = comp_w[(size_t)kk*128 + e];
          unsigned short h = f2bf(v);
          WHi[e*320+kk]=h; WLo[e*320+kk]=f2bf(v - bf2f(h));
        }
      } else {
        for (int kk=292;kk<320;++kk){ WHi[e*320+kk]=0; WLo[e*320+kk]=0; }
      }
    }
  } else {
    int g = (blk-1674)*256 + t;      // M*40 = 655360
    int row = g / 40, seg = g - row*40;
    const float* sr = str_fea + (size_t)row*F_;
    if (seg == 0) w_row[row] = sr[0];
    const float* af = af_table + (size_t)comp_fea[row]*92;
    const int c0 = seg*8;
    us8v hi, lo;
    #pragma unroll
    for (int e=0;e<8;++e){
      int kk = c0+e; float v;
      if (kk < 92) v = af[kk];
      else if (kk < 192) { float u = 1.f - sr[1+kk-92]; v = u*u; }
      else if (kk < 292) v = 1.f - sr[1+kk-192];
      else v = 0.f;
      unsigned short h = f2bf(v);
      hi[e] = h; lo[e] = f2bf(v - bf2f(h));
    }
    *(us8v*)(FHi + (size_t)row*320 + c0) = hi;
    *(us8v*)(FLo + (size_t)row*320 + c0) = lo;
  }
}

// ---------- embed GEMM (split bf16, 3-MFMA) + inline biasE + LN0 epilogue ----------
__global__ __launch_bounds__(256) void embgemm_kernel(
    const unsigned short* __restrict__ FHi, const unsigned short* __restrict__ FLo,
    const unsigned short* __restrict__ WHi, const unsigned short* __restrict__ WLo,
    const float* __restrict__ Cpart, const float* __restrict__ comp_b,
    const float* __restrict__ emb_b,
    const float* __restrict__ g0, const float* __restrict__ b0,
    float* __restrict__ x, float* __restrict__ x_init,
    unsigned short* __restrict__ xnb) {
  __shared__ unsigned short lds[24576];    // 48 KB
  unsigned short* AHi = lds;
  unsigned short* ALo = lds + 4096;
  unsigned short* BHi = lds + 8192;
  unsigned short* BLo = lds + 16384;
  const int bm = blockIdx.x*64;
  const int t = threadIdx.x, w = t>>6, l = t&63;
  f4v acc[8];
  #pragma unroll
  for (int i=0;i<8;++i) acc[i] = (f4v){0.f,0.f,0.f,0.f};
  const int srow = t>>3, sseg = t&7;
  for (int k0=0;k0<320;k0+=64){
    #pragma unroll
    for (int c=0;c<2;++c){
      int row = c*32+srow;
      GLOAD16(FHi + (size_t)(bm+row)*320 + k0 + ((sseg^(row&7))<<3), (char*)AHi + c*4096 + w*1024);
      GLOAD16(FLo + (size_t)(bm+row)*320 + k0 + ((sseg^(row&7))<<3), (char*)ALo + c*4096 + w*1024);
    }
    #pragma unroll
    for (int c=0;c<4;++c){
      int row = c*32+srow;
      GLOAD16(WHi + (size_t)row*320 + k0 + ((sseg^(row&7))<<3), (char*)BHi + c*4096 + w*1024);
      GLOAD16(WLo + (size_t)row*320 + k0 + ((sseg^(row&7))<<3), (char*)BLo + c*4096 + w*1024);
    }
    __syncthreads();
    #pragma unroll
    for (int ks=0;ks<2;++ks){
      int arow = w*16 + (l&15);
      int aswz = ((((l>>4)+ks*4) ^ (arow&7))<<4);
      s8v ah = *(const s8v*)((const char*)AHi + arow*128 + aswz);
      s8v al = *(const s8v*)((const char*)ALo + arow*128 + aswz);
      #pragma unroll
      for (int ct=0;ct<8;++ct){
        int col = ct*16 + (l&15);
        int bswz = ((((l>>4)+ks*4) ^ (col&7))<<4);
        s8v bh = *(const s8v*)((const char*)BHi + col*128 + bswz);
        s8v bl = *(const s8v*)((const char*)BLo + col*128 + bswz);
        acc[ct] = MFMA16(ah, bh, acc[ct]);
        acc[ct] = MFMA16(ah, bl, acc[ct]);
        acc[ct] = MFMA16(al, bh, acc[ct]);
      }
    }
    __syncthreads();
  }
  float vv[8][4], gc[8], bc[8];
  #pragma unroll
  for (int ct=0;ct<8;++ct){
    int c = ct*16 + (l&15);
    float be = comp_b[c] + emb_b[c];
    for (int p=0;p<10;++p) be += Cpart[p*128+c];
    gc[ct] = g0[c]; bc[ct] = b0[c];
    #pragma unroll
    for (int r=0;r<4;++r) vv[ct][r] = acc[ct][r] + be;
  }
  #pragma unroll
  for (int r=0;r<4;++r){
    float s=0.f, sq=0.f;
    #pragma unroll
    for (int ct=0;ct<8;++ct){ s += vv[ct][r]; sq += vv[ct][r]*vv[ct][r]; }
    #pragma unroll
    for (int m=1;m<16;m<<=1){ s += __shfl_xor(s,m,64); sq += __shfl_xor(sq,m,64); }
    float mean = s*(1.f/128.f);
    float rstd = rsqrtf(sq*(1.f/128.f) - mean*mean + 1e-5f);
    int row = bm + w*16 + (l>>4)*4 + r;
    #pragma unroll
    for (int ct=0;ct<8;++ct){
      int c = ct*16 + (l&15);
      float v = vv[ct][r];
      x[(size_t)row*128 + c] = v;
      x_init[(size_t)row*128 + c] = v;
      xnb[(size_t)row*128 + c] = f2bf((v-mean)*rstd*gc[ct] + bc[ct]);
    }
  }
}

// ---------- qkv GEMM v2: A staged once, 3 n-subtiles of 128 reuse it ----------
__global__ __launch_bounds__(256) void mgemm3_kernel(
    const unsigned short* __restrict__ A,
    const unsigned short* __restrict__ Bt,
    const float* __restrict__ bias,
    unsigned short* __restrict__ Cb,
    unsigned short* __restrict__ vT) {
  __shared__ char smem[65536];
  char* const Al = smem;            // 32 KB: A [128m][128k], two 64k halves
  char* const Bl = smem + 32768;    // 32 KB: B [128n][64k] x2 halves (per nt)
  unsigned short* const lds16 = (unsigned short*)(smem + 32768);  // epilogue reuse
  const int bm = blockIdx.x*128;
  const int bng = blockIdx.y*384;
  const int t = threadIdx.x;
  const int w = t>>6, l = t&63;
  const int wr = w>>1, wc = w&1;
  const int srow = t>>3, sseg = t&7;
  // stage A (both K halves) once
  #pragma unroll
  for (int kh=0;kh<2;++kh)
    #pragma unroll
    for (int c=0;c<4;++c){
      int row = c*32 + srow;
      GLOAD16(A + (size_t)(bm+row)*128 + kh*64 + ((sseg ^ (row&7))<<3),
              Al + kh*16384 + c*4096 + w*1024);
    }
  __syncthreads();
  #pragma unroll 1
  for (int nt=0; nt<3; ++nt){
    const int bn = bng + nt*128;
    // stage B (both K halves) for this n-subtile
    #pragma unroll
    for (int kh=0;kh<2;++kh)
      #pragma unroll
      for (int c=0;c<4;++c){
        int row = c*32 + srow;
        GLOAD16(Bt + (size_t)(bn+row)*128 + kh*64 + ((sseg ^ (row&7))<<3),
                Bl + kh*16384 + c*4096 + w*1024);
      }
    __syncthreads();
    f4v acc[4][4];
    #pragma unroll
    for (int i=0;i<4;++i)
      #pragma unroll
      for (int j=0;j<4;++j) acc[i][j] = (f4v){0.f,0.f,0.f,0.f};
    #pragma unroll
    for (int kh=0;kh<2;++kh){
      #pragma unroll
      for (int ks=0;ks<2;++ks){
        s8v bf[4];
        #pragma unroll
        for (int ct=0;ct<4;++ct){
          int col = wc*64 + ct*16 + (l&15);
          bf[ct] = *(const s8v*)(Bl + kh*16384 + col*128 + ((((l>>4)+ks*4) ^ (col&7))<<4));
        }
        #pragma unroll
        for (int rt=0;rt<4;++rt){
          int arow = wr*64 + rt*16 + (l&15);
          s8v af = *(const s8v*)(Al + kh*16384 + arow*128 + ((((l>>4)+ks*4) ^ (arow&7))<<4));
          #pragma unroll
          for (int ct=0;ct<4;++ct)
            acc[rt][ct] = MFMA16(af, bf[ct], acc[rt][ct]);
        }
      }
    }
    __syncthreads();   // B reads done before epilogue overwrites Bl region
    float bia[4];
    #pragma unroll
    for (int ct=0;ct<4;++ct) bia[ct] = bias[bn + wc*64 + ct*16 + (l&15)];
    if (bn < 1024) {
      #pragma unroll
      for (int rt=0;rt<4;++rt)
        #pragma unroll
        for (int ct=0;ct<4;++ct)
          #pragma unroll
          for (int r=0;r<4;++r){
            int rr = wr*64 + rt*16 + (l>>4)*4 + r;
            int cc = wc*64 + ct*16 + (l&15);
            lds16[rr*128 + cc] = f2bf(acc[rt][ct][r] + bia[ct]);
          }
      __syncthreads();
      #pragma unroll
      for (int it=0; it<8; ++it){
        int row = it*16 + (t>>4), seg = t&15;
        u4v v = *(const u4v*)(lds16 + row*128 + seg*8);
        *(u4v*)(Cb + (size_t)(bm+row)*1024 + bn + seg*8) = v;
      }
      __syncthreads();   // epilogue reads done before next nt's B staging
    } else {
      #pragma unroll
      for (int rt=0;rt<4;++rt)
        #pragma unroll
        for (int ct=0;ct<4;++ct){
          int rbase = bm + wr*64 + rt*16 + (l>>4)*4;
          int bb = rbase >> 9, nn = rbase & 511;
          int d = bn - 1024 + wc*64 + ct*16 + (l&15);
          unsigned int lo = (unsigned int)f2bf(acc[rt][ct][0] + bia[ct])
                          | ((unsigned int)f2bf(acc[rt][ct][1] + bia[ct])<<16);
          unsigned int hi = (unsigned int)f2bf(acc[rt][ct][2] + bia[ct])
                          | ((unsigned int)f2bf(acc[rt][ct][3] + bia[ct])<<16);
          uint2 pk; pk.x = lo; pk.y = hi;
          *(uint2*)(vT + ((size_t)(bb*512 + d))*512 + nn) = pk;
        }
      // no LDS use in vT epilogue; post-MFMA barrier above already protects Bl
    }
  }
}

// ---------- fused attention (single-QK) + tail (R18 structure, unchanged) ----------
#define STG_KH(dst, hh, j0s) { \
  _Pragma("unroll") \
  for (int c_=0;c_<8;++c_){ \
    int row_ = c_*32 + w*4 + (l>>4); \
    GLOAD16(qkb + (size_t)(b*512 + (j0s) + row_)*1024 + 512 + (hh)*128 + (((l&15) ^ (row_&7))<<3), \
            (dst) + c_*8192 + w*1024); } }

#define STG_VT(dst, j0s) { \
  _Pragma("unroll") \
  for (int c_=0;c_<4;++c_){ \
    int d_ = c_*128 + w*16 + (l>>2); \
    GLOAD16(vT + ((size_t)(b*512 + d_))*512 + (j0s) + (((l&3) ^ ((d_>>1)&3))<<3), \
            (dst) + c_*8192 + w*1024); } }

#define STG_B2(dst, k0s) { \
  _Pragma("unroll") \
  for (int c_=0;c_<4;++c_){ \
    int n_ = c_*32 + w*4 + (l>>4); \
    GLOAD16(outTl + (size_t)n_*512 + (k0s) + (((l&15) ^ (n_&7))<<3), \
            (dst) + (c_*32 + w*4)*256); } }

#define STG_F1() { \
  _Pragma("unroll") \
  for (int c2_=0;c2_<4;++c2_){ \
    int kh_ = c2_>>1, c_ = c2_&1; \
    int n_ = c_*64 + w*8 + (l>>3); \
    GLOAD16(ffnTl + (size_t)n_*128 + kh_*64 + (((l&7) ^ (n_&7))<<3), \
            ffnB + kh_*16384 + (c_*64 + w*8)*128); } }

__global__ __launch_bounds__(512, 2) void attnX_kernel(
    const unsigned short* __restrict__ qkb, const unsigned short* __restrict__ vT,
    const float* __restrict__ w_row,
    const unsigned short* __restrict__ outTl, const float* __restrict__ out_b,
    const unsigned short* __restrict__ ffnTl, const float* __restrict__ ffn_b,
    float* __restrict__ x, unsigned short* __restrict__ xnb,
    const float* __restrict__ g1, const float* __restrict__ b1,
    const float* __restrict__ g2, const float* __restrict__ b2) {
  __shared__ char smem[136704];
  char* const Kt0 = smem;
  char* const Kt1 = smem + 65536;
  char* const cALc = smem;
  unsigned short* const cAL = (unsigned short*)smem;
  char* const VbA = smem + 66560;               // 32 KB
  char* const VbB = smem + 99328;               // 32 KB
  float* const w_s    = (float*)(smem + 132096); // 512 f32
  float* const Spart  = (float*)(smem + 134144); // [2][64]
  float* const Rpart  = (float*)(smem + 134656); // [2][64]
  float* const rho_l  = (float*)(smem + 135424); // [4][64]
  float* const zinv_l = (float*)(smem + 136448); // [64]
  unsigned short* const outL = (unsigned short*)smem;  // [64][520]
  char* const BtA = smem + 66560;               // 32 KB (128k B tile)
  char* const BtB = smem + 99328;               // 32 KB
  float* const vst = (float*)(smem + 66560);    // 32 KB, overlays dead BtA
  char* const xnl  = smem;                      // 16 KB over dead outL
  char* const ffnB = smem + 16384;              // 32 KB over dead outL

  const int id = blockIdx.x;
  const int b  = (id & 7) | ((id >> 6) << 3);
  const int i0 = ((id >> 3) & 7) * 64;
  const int bm = b*512 + i0;
  const int t = threadIdx.x, w = t>>6, l = t&63;
  const int wi = w & 3, wd = w >> 2;
  const int ib = wi*16 + (l>>4)*4;
  const int arow = wi*16 + (l&15);
  const float SC2 = 1.4426950408889634f * 0.088388347648318447f; // log2e/sqrt(128)

  for (int j=t; j<512; j+=512) w_s[j] = w_row[b*512+j];

  float c_[2][8][4];
  #pragma unroll
  for (int tt=0;tt<2;++tt)
    #pragma unroll
    for (int js=0;js<8;++js)
      #pragma unroll
      for (int r=0;r<4;++r) c_[tt][js][r] = 0.f;

  STG_KH(Kt0, 0, 0);
  __syncthreads();

  char* Kc = Kt0; char* Kn = Kt1;
  #pragma unroll 1
  for (int h=0; h<4; ++h){
    s8v qf[4];
    {
      const unsigned short* qbase = qkb + ((size_t)(bm + arow))*1024 + h*128;
      #pragma unroll
      for (int ks=0;ks<4;++ks) qf[ks] = *(const s8v*)(qbase + ks*32 + (l>>4)*8);
    }
    float Ex[2][8][4];
    #pragma unroll
    for (int tt=0; tt<2; ++tt){
      if (tt==0) { STG_KH(Kn, h, 256); }
      else if (h<3) { STG_KH(Kn, h+1, 0); }
      __builtin_amdgcn_s_setprio(1);
      #pragma unroll
      for (int jsub=0;jsub<8;++jsub){
        const int jcol = wd*128 + jsub*16 + (l&15);
        f4v a = (f4v){0.f,0.f,0.f,0.f};
        #pragma unroll
        for (int ks=0;ks<4;++ks){
          int g = ks*4 + (l>>4);
          s8v kf = *(const s8v*)(Kc + jcol*256 + ((g ^ (jcol&7))<<4));
          a = MFMA16(qf[ks], kf, a);
        }
        #pragma unroll
        for (int r=0;r<4;++r) Ex[tt][jsub][r] = exp2f(a[r]*SC2);
      }
      __builtin_amdgcn_s_setprio(0);
      __syncthreads();
      char* tmp = Kc; Kc = Kn; Kn = tmp;
    }
    float sp[4] = {0.f,0.f,0.f,0.f};
    float rp[4] = {0.f,0.f,0.f,0.f};
    #pragma unroll
    for (int tt=0;tt<2;++tt)
      #pragma unroll
      for (int jsub=0;jsub<8;++jsub){
        int jg = tt*256 + wd*128 + jsub*16 + (l&15);
        float wv = w_s[jg];
        float mw = (wv != 0.f) ? 1.f : 0.f;
        #pragma unroll
        for (int r=0;r<4;++r){
          sp[r] += Ex[tt][jsub][r]*mw;
          rp[r] += Ex[tt][jsub][r]*wv;
        }
      }
    #pragma unroll
    for (int r=0;r<4;++r){
      float s = sp[r], rv = rp[r];
      s += __shfl_xor(s,1,64); rv += __shfl_xor(rv,1,64);
      s += __shfl_xor(s,2,64); rv += __shfl_xor(rv,2,64);
      s += __shfl_xor(s,4,64); rv += __shfl_xor(rv,4,64);
      s += __shfl_xor(s,8,64); rv += __shfl_xor(rv,8,64);
      sp[r] = s; rp[r] = rv;
    }
    if ((l&15)==0){
      #pragma unroll
      for (int r=0;r<4;++r){
        Spart[wd*64 + ib + r] = sp[r];
        Rpart[wd*64 + ib + r] = rp[r];
      }
    }
    __syncthreads();
    if (t < 64){
      float S0 = Spart[t] + Spart[64+t];
      float R = Rpart[t] + Rpart[64+t];
      rho_l[h*64+t] = R/S0;
    }
    float siv[4];
    #pragma unroll
    for (int r=0;r<4;++r)
      siv[r] = 1.f/(Spart[ib + r] + Spart[64 + ib + r]);
    #pragma unroll
    for (int tt=0;tt<2;++tt)
      #pragma unroll
      for (int jsub=0;jsub<8;++jsub)
        #pragma unroll
        for (int r=0;r<4;++r)
          c_[tt][jsub][r] += Ex[tt][jsub][r]*siv[r];
  }

  __syncthreads();
  STG_VT(VbA, 0);
  if (t < 64)
    zinv_l[t] = 1.f/(rho_l[t] + rho_l[64+t] + rho_l[128+t] + rho_l[192+t]);
  #pragma unroll
  for (int tt=0;tt<2;++tt)
    #pragma unroll
    for (int jsub=0;jsub<8;++jsub){
      int jg = tt*256 + wd*128 + jsub*16 + (l&15);
      float wv = w_s[jg];
      #pragma unroll
      for (int r=0;r<4;++r)
        cAL[(ib+r)*520 + jg] = f2bf(c_[tt][jsub][r]*wv);
    }
  __syncthreads();
  float zv[4][4];
  #pragma unroll
  for (int ig=0;ig<4;++ig)
    #pragma unroll
    for (int r=0;r<4;++r) zv[ig][r] = zinv_l[ig*16 + (l>>4)*4 + r];

  f4v pacc[4][4];
  #pragma unroll
  for (int ig=0;ig<4;++ig)
    #pragma unroll
    for (int ds=0;ds<4;++ds) pacc[ig][ds] = (f4v){0.f,0.f,0.f,0.f};
  {
    char* Vc = VbA; char* Vn = VbB;
    #pragma unroll 1
    for (int vt=0; vt<16; ++vt){
      if (vt < 15) STG_VT(Vn, (vt+1)*32);
      int kidx = l>>4;
      s8v af[4];
      #pragma unroll
      for (int ig=0;ig<4;++ig)
        af[ig] = *(const s8v*)(cALc + (ig*16 + (l&15))*1040 + vt*64 + (kidx<<4));
      __builtin_amdgcn_s_setprio(1);
      #pragma unroll
      for (int dsub=0;dsub<4;++dsub){
        int d = w*64 + dsub*16 + (l&15);
        s8v vf = *(const s8v*)(Vc + d*64 + ((kidx ^ ((d>>1)&3))<<4));
        #pragma unroll
        for (int ig=0;ig<4;++ig)
          pacc[ig][dsub] = MFMA16(af[ig], vf, pacc[ig][dsub]);
      }
      __builtin_amdgcn_s_setprio(0);
      __syncthreads();
      char* tmp = Vc; Vc = Vn; Vn = tmp;
    }
  }

  #pragma unroll
  for (int ig=0;ig<4;++ig)
    #pragma unroll
    for (int dsub=0;dsub<4;++dsub){
      int d = w*64 + dsub*16 + (l&15);
      #pragma unroll
      for (int r=0;r<4;++r)
        outL[(ig*16 + (l>>4)*4 + r)*520 + d] = f2bf(pacc[ig][dsub][r]*zv[ig][r]);
    }
  STG_B2(BtA, 0);
  __syncthreads();

  f4v acc1[4];
  #pragma unroll
  for (int ct=0;ct<4;++ct) acc1[ct] = (f4v){0.f,0.f,0.f,0.f};
  {
    char* Bc = BtA; char* Bn = BtB;
    #pragma unroll 1
    for (int tt=0; tt<4; ++tt){
      if (tt < 3) STG_B2(Bn, (tt+1)*128);
      __builtin_amdgcn_s_setprio(1);
      #pragma unroll
      for (int ks=0;ks<4;++ks){
        int kidx = (l>>4) + ks*4;
        s8v af = *(const s8v*)((const char*)outL + arow*1040 + tt*256 + (kidx<<4));
        #pragma unroll
        for (int ct=0;ct<4;++ct){
          int n = wd*64 + ct*16 + (l&15);
          s8v bf = *(const s8v*)(Bc + n*256 + ((kidx ^ (n&7))<<4));
          acc1[ct] = MFMA16(af, bf, acc1[ct]);
        }
      }
      __builtin_amdgcn_s_setprio(0);
      __syncthreads();
      char* tmp = Bc; Bc = Bn; Bn = tmp;
    }
  }

  #pragma unroll
  for (int ct=0;ct<4;++ct){
    int cc = wd*64 + ct*16 + (l&15);
    float ob = out_b[cc];
    #pragma unroll
    for (int r=0;r<4;++r){
      int rr = wi*16 + (l>>4)*4 + r;
      vst[rr*128 + cc] = acc1[ct][r] + ob + x[(size_t)(bm+rr)*128 + cc];
    }
  }
  STG_F1();
  __syncthreads();

  {
    const float2 g1v = *(const float2*)(g1 + l*2);
    const float2 b1v = *(const float2*)(b1 + l*2);
    #pragma unroll
    for (int rr=0; rr<8; ++rr){
      int row = w*8 + rr;
      float2 vv = *(const float2*)&vst[row*128 + l*2];
      float s = vv.x+vv.y, sq = vv.x*vv.x + vv.y*vv.y;
      #pragma unroll
      for (int m=1;m<64;m<<=1){ s += __shfl_xor(s,m,64); sq += __shfl_xor(sq,m,64); }
      float mean = s*(1.f/128.f);
      float rstd = rsqrtf(sq*(1.f/128.f) - mean*mean + 1e-5f);
      float xa = (vv.x-mean)*rstd*g1v.x + b1v.x;
      float xb = (vv.y-mean)*rstd*g1v.y + b1v.y;
      int col = l*2;
      int byte = row*256 + (((col>>3) ^ (row&7))<<4) + ((col&7)<<1);
      unsigned int pk = (unsigned int)f2bf(xa) | ((unsigned int)f2bf(xb)<<16);
      *(unsigned int*)(xnl + byte) = pk;
    }
  }
  __syncthreads();

  f4v acc2[4];
  #pragma unroll
  for (int ct=0;ct<4;++ct) acc2[ct] = (f4v){0.f,0.f,0.f,0.f};
  __builtin_amdgcn_s_setprio(1);
  #pragma unroll
  for (int ks2=0;ks2<4;++ks2){
    int kidx2 = (l>>4) + ks2*4;
    s8v af = *(const s8v*)(xnl + arow*256 + ((kidx2 ^ (arow&7))<<4));
    int kh = ks2>>1, ksb = ks2&1;
    int kb = (l>>4) + ksb*4;
    #pragma unroll
    for (int ct=0;ct<4;++ct){
      int n = wd*64 + ct*16 + (l&15);
      s8v bf = *(const s8v*)(ffnB + kh*16384 + n*128 + ((kb ^ (n&7))<<4));
      acc2[ct] = MFMA16(af, bf, acc2[ct]);
    }
  }
  __builtin_amdgcn_s_setprio(0);
  #pragma unroll
  for (int ct=0;ct<4;++ct){
    int cc = wd*64 + ct*16 + (l&15);
    float fb = ffn_b[cc];
    #pragma unroll
    for (int r=0;r<4;++r){
      int rr = wi*16 + (l>>4)*4 + r;
      vst[rr*128 + cc] += softplus_f(acc2[ct][r] + fb);
    }
  }
  __syncthreads();

  {
    const float2 g1v = *(const float2*)(g1 + l*2);
    const float2 b1v = *(const float2*)(b1 + l*2);
    #pragma unroll
    for (int rr=0; rr<8; ++rr){
      int row = w*8 + rr;
      float2 vv = *(const float2*)&vst[row*128 + l*2];
      float s = vv.x+vv.y, sq = vv.x*vv.x + vv.y*vv.y;
      #pragma unroll
      for (int m=1;m<64;m<<=1){ s += __shfl_xor(s,m,64); sq += __shfl_xor(sq,m,64); }
      float mean = s*(1.f/128.f);
      float rstd = rsqrtf(sq*(1.f/128.f) - mean*mean + 1e-5f);
      float xa = (vv.x-mean)*rstd*g1v.x + b1v.x;
      float xb = (vv.y-mean)*rstd*g1v.y + b1v.y;
      float2 xo; xo.x = xa; xo.y = xb;
      *(float2*)(x + (size_t)(bm+row)*128 + l*2) = xo;
      if (g2) {
        float s2 = xa+xb, sq2 = xa*xa + xb*xb;
        #pragma unroll
        for (int m=1;m<64;m<<=1){ s2 += __shfl_xor(s2,m,64); sq2 += __shfl_xor(sq2,m,64); }
        float mean2 = s2*(1.f/128.f);
        float rstd2 = rsqrtf(sq2*(1.f/128.f) - mean2*mean2 + 1e-5f);
        const float2 g2v = *(const float2*)(g2 + l*2);
        const float2 b2v = *(const float2*)(b2 + l*2);
        float ya = (xa-mean2)*rstd2*g2v.x + b2v.x;
        float yb = (xb-mean2)*rstd2*g2v.y + b2v.y;
        unsigned int pk = (unsigned int)f2bf(ya) | ((unsigned int)f2bf(yb)<<16);
        *(unsigned int*)(xnb + (size_t)(bm+row)*128 + l*2) = pk;
      }
    }
  }
}

// ---------- fused pooling + final (one dispatch) ----------
__global__ __launch_bounds__(256) void poolfinal_kernel(
    const float* __restrict__ x, const float* __restrict__ x_init,
    const float* __restrict__ w_row,
    const float* __restrict__ g, const float* __restrict__ bt,
    const float* __restrict__ fw, const float* __restrict__ fb,
    float* __restrict__ out) {
  __shared__ float red[2][128];
  __shared__ float red2[4];
  __shared__ float red3[2];
  const int b = blockIdx.x;
  const int t = threadIdx.x;
  const int e = t & 127, half = t >> 7;
  float acc = 0.f;
  for (int n = half*256; n < half*256+256; ++n) {
    float w = w_row[(size_t)b*N_ + n];
    size_t o = ((size_t)b*N_ + n)*E_ + e;
    acc += w * (x[o] + x_init[o]);
  }
  red[half][e] = acc;
  __syncthreads();
  float s=0.f, sq=0.f, v=0.f;
  if (t < 128) {
    v = red[0][t] + red[1][t];
    s = v; sq = v*v;
    #pragma unroll
    for (int m = 1; m < 64; m <<= 1) { s += __shfl_xor(s, m, 64); sq += __shfl_xor(sq, m, 64); }
    if ((t&63) == 0) { red2[(t>>6)*2] = s; red2[(t>>6)*2+1] = sq; }
  }
  __syncthreads();
  float p = 0.f;
  if (t < 128) {
    s = red2[0] + red2[2]; sq = red2[1] + red2[3];
    float mean = s*(1.f/E_), var = sq*(1.f/E_) - mean*mean;
    float rstd = rsqrtf(var + 1e-5f);
    float xl = (v - mean)*rstd*g[t] + bt[t];
    p = xl * fw[t];
    #pragma unroll
    for (int m = 1; m < 64; m <<= 1) p += __shfl_xor(p, m, 64);
    if ((t&63) == 0) red3[t>>6] = p;
  }
  __syncthreads();
  if (t == 0) out[b] = red3[0] + red3[1] + fb[0];
}

extern "C" void kernel_launch(void* const* d_in, const int* in_sizes, int n_in,
                              void* d_out, int out_size, void* d_ws, size_t ws_size,
                              hipStream_t stream) {
  (void)in_sizes; (void)n_in; (void)out_size; (void)ws_size;
  const float* str_fea  = (const float*)d_in[0];
  const int*   comp_fea = (const int*)  d_in[1];
  const float* af_table = (const float*)d_in[3];
  const float* comp_w   = (const float*)d_in[4];
  const float* comp_b   = (const float*)d_in[5];
  const float* emb_w    = (const float*)d_in[6];
  const float* emb_b    = (const float*)d_in[7];
  const float* ln_g     = (const float*)d_in[8];
  const float* ln_b     = (const float*)d_in[9];
  const float* wq       = (const float*)d_in[10];
  const float* bq       = (const float*)d_in[11];
  const float* wk       = (const float*)d_in[12];
  const float* bk       = (const float*)d_in[13];
  const float* wv       = (const float*)d_in[14];
  const float* bv       = (const float*)d_in[15];
  const float* inproj_w = (const float*)d_in[16];
  const float* inproj_b = (const float*)d_in[17];
  const float* out_w    = (const float*)d_in[18];
  const float* out_b    = (const float*)d_in[19];
  const float* ffn_w    = (const float*)d_in[20];
  const float* ffn_b    = (const float*)d_in[21];
  const float* ln2_g    = (const float*)d_in[22];
  const float* ln2_b    = (const float*)d_in[23];
  const float* final_w  = (const float*)d_in[24];
  const float* final_b  = (const float*)d_in[25];
  float* out = (float*)d_out;

  float* ws = (float*)d_ws;
  size_t off = 0;
  float* x      = ws + off; off += 2097152;
  float* x_init = ws + off; off += 2097152;
  float* w_row  = ws + off; off += 16384;
  unsigned short* xnb  = (unsigned short*)(ws + off); off += 1048576;   // [M][128]
  unsigned short* qkb  = (unsigned short*)(ws + off); off += 8388608;   // [M][1024]
  unsigned short* vTb  = (unsigned short*)(ws + off); off += 4194304;   // [B][512][512]
  float* bpart  = ws + off; off += 24576;    // [6][8][512]
  float* effpart= ws + off; off += 3145728;  // [8][6][8][64][128] f32
  float* bqkv   = ws + off; off += 4608;
  unsigned short* wqkvT = (unsigned short*)(ws + off); off += 294912;   // [3][1536][128]
  unsigned short* outT  = (unsigned short*)(ws + off); off += 98304;    // [3][128][512]
  unsigned short* ffnT  = (unsigned short*)(ws + off); off += 24576;    // [3][128][128]
  unsigned short* FHi   = (unsigned short*)(ws + off); off += 2621440;  // [M][320]
  unsigned short* FLo   = (unsigned short*)(ws + off); off += 2621440;
  unsigned short* WHi   = (unsigned short*)(ws + off); off += 20480;    // [128][320]
  unsigned short* WLo   = (unsigned short*)(ws + off); off += 20480;
  float* Cpart  = ws + off; off += 1280;

  prepA_kernel<<<432, 256, 0, stream>>>(wq, wk, bq, bk, inproj_w, effpart, bpart);
  prepB_kernel<<<4234, 256, 0, stream>>>(effpart, bpart, wv, out_w, ffn_w,
                                         inproj_b, bv, emb_w, comp_w,
                                         str_fea, comp_fea, af_table,
                                         wqkvT, outT, ffnT, bqkv,
                                         WHi, WLo, Cpart, FHi, FLo, w_row);
  embgemm_kernel<<<M_/64, 256, 0, stream>>>(FHi, FLo, WHi, WLo, Cpart, comp_b, emb_b,
                                            ln_g, ln_b, x, x_init, xnb);

  for (int l = 0; l < L_; ++l) {
    mgemm3_kernel<<<dim3(M_/128, 4), 256, 0, stream>>>(
        xnb, wqkvT + (size_t)l*196608, bqkv + l*1536, qkb, vTb);
    attnX_kernel<<<256, 512, 0, stream>>>(
        qkb, vTb, w_row,
        outT + (size_t)l*65536, out_b + (size_t)l*E_,
        ffnT + (size_t)l*16384, ffn_b + (size_t)l*E_,
        x, xnb, ln_g + l*E_, ln_b + l*E_,
        (l < 2) ? (ln_g + (l+1)*E_) : nullptr,
        (l < 2) ? (ln_b + (l+1)*E_) : nullptr);
  }

  poolfinal_kernel<<<B_, 256, 0, stream>>>(x, x_init, w_row, ln2_g, ln2_b,
                                           final_w, final_b, out);
}